// Round 6
// baseline (898.189 us; speedup 1.0000x reference)
//
#include <hip/hip_runtime.h>
#include <hip/hip_bf16.h>

typedef __hip_bfloat16 bf16;
typedef unsigned short u16;
typedef unsigned int u32;
typedef __attribute__((ext_vector_type(8))) short short8;
typedef __attribute__((ext_vector_type(4))) float floatx4;

#define N_NODES 50000
#define N_EDGES 800000
#define DIM 128
#define NBUCK 391          // ceil(50000/128); bucket = dst >> 7
#define CAP 2560           // per-bucket capacity (mean 2046, sigma ~45 -> 11 sigma margin)
#define T_EDGES 8192       // edges per sort block

__device__ __forceinline__ u16 f2bfbits(float f) {
    bf16 h = __float2bfloat16(f);
    return *(u16*)&h;
}
__device__ __forceinline__ unsigned pack2(float a, float b) {
    return (unsigned)f2bfbits(a) | ((unsigned)f2bfbits(b) << 16);
}

// ---------------- detect int64-vs-int32 edge storage + zero cursors/stats ----------------
__global__ void detect_kernel(const int* __restrict__ ei, int* __restrict__ flags,
                              int* __restrict__ gcur, float* __restrict__ stats) {
    int t = threadIdx.x;
    if (t < NBUCK) gcur[t] = 0;
    stats[t] = 0.f;                      // 512 threads == 4*128 stats slots
    if (t == 0) {
        int acc = 0;
        for (int k = 0; k < 64; k++) acc |= ei[2 * k + 1];
        flags[1] = (acc == 0) ? 1 : 0;
    }
}

// ---------------- pack edges: packed[e] = src | (dst << 16) ----------------
__global__ void pack_kernel(const int* __restrict__ ei, const int* __restrict__ flags,
                            u32* __restrict__ packed) {
    int is64 = flags[1];
    int base = blockIdx.x * 1024 + threadIdx.x;
    #pragma unroll
    for (int j = 0; j < 4; j++) {
        int e = base + j * 256;
        if (e < N_EDGES) {
            int js = e, jd = N_EDGES + e;
            if (is64) { js = 2 * e; jd = 2 * (N_EDGES + e); }
            u32 s = (u32)ei[js], d = (u32)ei[jd];
            packed[e] = s | (d << 16);
        }
    }
}

// ---------------- tile counting-sort into 391 dst-buckets ----------------
// Block sorts T_EDGES edges in LDS, appends contiguous per-bucket runs to global.
__launch_bounds__(256)
__global__ void sort_kernel(const u32* __restrict__ packed, u32* __restrict__ gbuck,
                            int* __restrict__ gcur) {
    __shared__ int hist[512];
    __shared__ int offs[512];
    __shared__ int partial[256];
    __shared__ int cur[NBUCK];
    __shared__ int gbase[NBUCK];
    __shared__ u32 buf[T_EDGES];
    int t = threadIdx.x;
    int e0 = blockIdx.x * T_EDGES;
    int n = N_EDGES - e0; if (n > T_EDGES) n = T_EDGES;

    for (int i = t; i < 512; i += 256) hist[i] = 0;
    for (int i = t; i < NBUCK; i += 256) cur[i] = 0;
    __syncthreads();

    u32 ed[T_EDGES / 256];
    #pragma unroll
    for (int j = 0; j < T_EDGES / 256; j++) {
        int idx = j * 256 + t;
        if (idx < n) {
            u32 p = packed[e0 + idx];
            ed[j] = p;
            atomicAdd(&hist[p >> 23], 1);   // bucket = dst>>7 = p>>23
        }
    }
    __syncthreads();

    // exclusive scan of hist[512] with 256 threads (2 elems each)
    int a0 = hist[2 * t], a1 = hist[2 * t + 1];
    partial[t] = a0 + a1;
    __syncthreads();
    for (int d = 1; d < 256; d <<= 1) {
        int v = (t >= d) ? partial[t - d] : 0;
        __syncthreads();
        partial[t] += v;
        __syncthreads();
    }
    int ex = partial[t] - (a0 + a1);
    offs[2 * t] = ex; offs[2 * t + 1] = ex + a0;
    __syncthreads();

    // scatter into LDS in bucket order
    #pragma unroll
    for (int j = 0; j < T_EDGES / 256; j++) {
        int idx = j * 256 + t;
        if (idx < n) {
            int b = ed[j] >> 23;
            int s = offs[b] + atomicAdd(&cur[b], 1);
            buf[s] = ed[j];
        }
    }
    // reserve global space per bucket
    for (int i = t; i < NBUCK; i += 256) {
        int c = hist[i];
        gbase[i] = c ? atomicAdd(&gcur[i], c) : 0;
    }
    __syncthreads();

    // copy out contiguous runs (wave per bucket round-robin)
    int wv = t >> 6, lane = t & 63;
    for (int b = wv; b < NBUCK; b += 4) {
        int c = hist[b], o = offs[b];
        long gb = (long)b * CAP + gbase[b];
        for (int j = lane; j < c; j += 64) gbuck[gb + j] = buf[o + j];
    }
}

// ---------------- fused gather-aggregate: h = (1+eps)*x + sum_{j in N(i)} x_j ----------------
// Block b owns nodes [b*128, b*128+128); accumulates into 64 KB LDS tile via ds_add_f32.
// Edge loop: lane holds feats {lane, lane+64} -> conflict-free LDS atomics; 4x unrolled.
__launch_bounds__(256)
__global__ void gather_agg(const float* __restrict__ x, const u32* __restrict__ gbuck,
                           const int* __restrict__ gcur, const float* __restrict__ epsp,
                           unsigned* __restrict__ hw) {
    __shared__ float sh[128 * 128];   // 64 KB
    int t = threadIdx.x, lane = t & 63, wv = t >> 6;
    int b = blockIdx.x;
    #pragma unroll
    for (int j = 0; j < 16; j++) *(floatx4*)&sh[(j * 256 + t) * 4] = (floatx4){0.f, 0.f, 0.f, 0.f};
    __syncthreads();

    int cnt = gcur[b];
    long base = (long)b * CAP;
    int i = wv;
    for (; i + 12 < cnt; i += 16) {
        u32 p0 = gbuck[base + i], p1 = gbuck[base + i + 4];
        u32 p2 = gbuck[base + i + 8], p3 = gbuck[base + i + 12];
        int s0 = p0 & 0xFFFF, d0 = (p0 >> 16) & 127;
        int s1 = p1 & 0xFFFF, d1 = (p1 >> 16) & 127;
        int s2 = p2 & 0xFFFF, d2 = (p2 >> 16) & 127;
        int s3 = p3 & 0xFFFF, d3 = (p3 >> 16) & 127;
        float a0 = x[s0 * DIM + lane], b0 = x[s0 * DIM + 64 + lane];
        float a1 = x[s1 * DIM + lane], b1 = x[s1 * DIM + 64 + lane];
        float a2 = x[s2 * DIM + lane], b2 = x[s2 * DIM + 64 + lane];
        float a3 = x[s3 * DIM + lane], b3 = x[s3 * DIM + 64 + lane];
        atomicAdd(&sh[d0 * DIM + lane], a0);      atomicAdd(&sh[d0 * DIM + 64 + lane], b0);
        atomicAdd(&sh[d1 * DIM + lane], a1);      atomicAdd(&sh[d1 * DIM + 64 + lane], b1);
        atomicAdd(&sh[d2 * DIM + lane], a2);      atomicAdd(&sh[d2 * DIM + 64 + lane], b2);
        atomicAdd(&sh[d3 * DIM + lane], a3);      atomicAdd(&sh[d3 * DIM + 64 + lane], b3);
    }
    for (; i < cnt; i += 4) {
        u32 p = gbuck[base + i];
        int s = p & 0xFFFF, d = (p >> 16) & 127;
        atomicAdd(&sh[d * DIM + lane],      x[s * DIM + lane]);
        atomicAdd(&sh[d * DIM + 64 + lane], x[s * DIM + 64 + lane]);
    }
    __syncthreads();

    // self term + writeout (bf16 packed, coalesced)
    float ep1 = 1.0f + epsp[0];
    for (int nn = wv; nn < 128; nn += 4) {
        int node = b * 128 + nn;
        if (node < N_NODES) {
            float2 xv = *(const float2*)&x[node * DIM + lane * 2];
            float v0 = sh[nn * DIM + lane * 2]     + ep1 * xv.x;
            float v1 = sh[nn * DIM + lane * 2 + 1] + ep1 * xv.y;
            hw[node * 64 + lane] = pack2(v0, v1);
        }
    }
}

// ---------------- MFMA GEMM: Y[m][o] = sum_k T(A[m][k]) * W[o][k] + bias[o] ----------------
template<int TRANSFORM>
__launch_bounds__(256)
__global__ void gemm_mfma(const void* Ap, const float* __restrict__ Wp,
                          const float* __restrict__ bias,
                          const float* __restrict__ scale, const float* __restrict__ shift,
                          float* Yp, float* __restrict__ osum, float* __restrict__ osq) {
    __shared__ u16 sW[128 * 136];
    __shared__ float sScale[128], sShift[128], sBias[128], sSum[128], sSq[128];
    int t = threadIdx.x, lane = t & 63, wv = t >> 6;

    #pragma unroll
    for (int it = 0; it < 16; it++) {
        int q = it * 256 + t;
        int r = q >> 5, cq = q & 31;
        floatx4 w = ((const floatx4*)Wp)[q];
        u16 bb[4] = {f2bfbits(w[0]), f2bfbits(w[1]), f2bfbits(w[2]), f2bfbits(w[3])};
        *(uint2*)&sW[r * 136 + cq * 4] = *(uint2*)bb;
    }
    if (t < 128) {
        sSum[t] = 0.f; sSq[t] = 0.f; sBias[t] = bias[t];
        if (TRANSFORM) { sScale[t] = scale[t]; sShift[t] = shift[t]; }
    }
    __syncthreads();

    int tile = blockIdx.x * 4 + wv;
    if (tile < (N_NODES / 16)) {
        int col0 = lane & 15, quad = lane >> 4;
        int mrow = tile * 16 + col0;

        short8 afr[4];
        if (TRANSFORM == 0) {
            const u16* A = (const u16*)Ap;
            #pragma unroll
            for (int ks = 0; ks < 4; ks++)
                afr[ks] = *(const short8*)&A[mrow * DIM + ks * 32 + quad * 8];
        } else {
            const float* A = (const float*)Ap;
            #pragma unroll
            for (int ks = 0; ks < 4; ks++) {
                int kb = ks * 32 + quad * 8;
                floatx4 v0 = *(const floatx4*)&A[mrow * DIM + kb];
                floatx4 v1 = *(const floatx4*)&A[mrow * DIM + kb + 4];
                short8 r;
                #pragma unroll
                for (int j = 0; j < 4; j++) {
                    r[j]     = (short)f2bfbits(fmaxf(fmaf(v0[j], sScale[kb + j],     sShift[kb + j]),     0.f));
                    r[j + 4] = (short)f2bfbits(fmaxf(fmaf(v1[j], sScale[kb + 4 + j], sShift[kb + 4 + j]), 0.f));
                }
                afr[ks] = r;
            }
        }

        floatx4 acc[8];
        #pragma unroll
        for (int nt = 0; nt < 8; nt++) acc[nt] = (floatx4){0.f, 0.f, 0.f, 0.f};
        #pragma unroll
        for (int ks = 0; ks < 4; ks++) {
            #pragma unroll
            for (int nt = 0; nt < 8; nt++) {
                short8 bfr = *(const short8*)&sW[(nt * 16 + col0) * 136 + ks * 32 + quad * 8];
                acc[nt] = __builtin_amdgcn_mfma_f32_16x16x32_bf16(afr[ks], bfr, acc[nt], 0, 0, 0);
            }
        }

        #pragma unroll
        for (int nt = 0; nt < 8; nt++) {
            int col = nt * 16 + col0;
            float bb = sBias[col];
            float o0 = acc[nt][0] + bb, o1 = acc[nt][1] + bb;
            float o2 = acc[nt][2] + bb, o3 = acc[nt][3] + bb;
            int rbase = tile * 16 + quad * 4;
            Yp[(rbase + 0) * DIM + col] = o0;
            Yp[(rbase + 1) * DIM + col] = o1;
            Yp[(rbase + 2) * DIM + col] = o2;
            Yp[(rbase + 3) * DIM + col] = o3;
            float s = o0 + o1 + o2 + o3;
            float q = o0 * o0 + o1 * o1 + o2 * o2 + o3 * o3;
            s += __shfl_xor(s, 16); s += __shfl_xor(s, 32);
            q += __shfl_xor(q, 16); q += __shfl_xor(q, 32);
            if (quad == 0) { atomicAdd(&sSum[col], s); atomicAdd(&sSq[col], q); }
        }
    }
    __syncthreads();
    if (t < 128) { atomicAdd(&osum[t], sSum[t]); atomicAdd(&osq[t], sSq[t]); }
}

__global__ void finalize_kernel(const float* __restrict__ sum, const float* __restrict__ sumsq,
                                const float* __restrict__ gamma, const float* __restrict__ beta,
                                float* __restrict__ scale, float* __restrict__ shift) {
    int c = threadIdx.x;
    if (c < 128) {
        float m = sum[c] * (1.0f / N_NODES);
        float v = sumsq[c] * (1.0f / N_NODES) - m * m;
        v = fmaxf(v, 0.0f);
        float rs = rsqrtf(v + 1e-5f);
        float sc = gamma[c] * rs;
        scale[c] = sc;
        shift[c] = beta[c] - m * sc;
    }
}

__global__ void output_kernel(const float* __restrict__ Y, const float* __restrict__ scale,
                              const float* __restrict__ shift, float* __restrict__ out) {
    int i = (blockIdx.x * blockDim.x + threadIdx.x) * 8;
    if (i >= N_NODES * DIM) return;
    int c = i & 127;
    floatx4 v0 = *(const floatx4*)&Y[i];
    floatx4 v1 = *(const floatx4*)&Y[i + 4];
    floatx4 o0, o1;
    #pragma unroll
    for (int j = 0; j < 4; j++) {
        o0[j] = fmaxf(fmaf(v0[j], scale[c + j],     shift[c + j]),     0.f);
        o1[j] = fmaxf(fmaf(v1[j], scale[c + 4 + j], shift[c + 4 + j]), 0.f);
    }
    *(floatx4*)&out[i] = o0;
    *(floatx4*)&out[i + 4] = o1;
}

extern "C" void kernel_launch(void* const* d_in, const int* in_sizes, int n_in,
                              void* d_out, int out_size, void* d_ws, size_t ws_size,
                              hipStream_t stream) {
    const float* x   = (const float*)d_in[0];
    const int* eraw  = (const int*)d_in[1];
    const float* eps = (const float*)d_in[3];
    const float* W1  = (const float*)d_in[4];
    const float* b1  = (const float*)d_in[5];
    const float* g1  = (const float*)d_in[6];
    const float* be1 = (const float*)d_in[7];
    const float* W2  = (const float*)d_in[8];
    const float* b2  = (const float*)d_in[9];
    const float* g2  = (const float*)d_in[10];
    const float* be2 = (const float*)d_in[11];

    char* ws = (char*)d_ws;
    size_t off = 0;
    unsigned* h = (unsigned*)(ws + off); off += (size_t)N_NODES * DIM * 2;   // bf16, 12.8 MB
    float* y = (float*)(ws + off);       off += (size_t)N_NODES * DIM * 4;   // fp32, 25.6 MB
    float* stats = (float*)(ws + off);   off += 4 * 128 * 4;
    float* sum1 = stats, *sq1 = stats + 128, *sum2 = stats + 256, *sq2 = stats + 384;
    float* scale1 = (float*)(ws + off);  off += 128 * 4;
    float* shift1 = (float*)(ws + off);  off += 128 * 4;
    float* scale2 = (float*)(ws + off);  off += 128 * 4;
    float* shift2 = (float*)(ws + off);  off += 128 * 4;
    u32* packed = (u32*)(ws + off);      off += (size_t)N_EDGES * 4;         // 3.2 MB
    u32* gbuck = (u32*)(ws + off);       off += (size_t)NBUCK * CAP * 4;     // 4.0 MB
    int* gcur = (int*)(ws + off);        off += 512 * 4;
    int* flags = (int*)(ws + off);       off += 16 * 4;

    detect_kernel<<<1, 512, 0, stream>>>(eraw, flags, gcur, stats);
    pack_kernel<<<(N_EDGES + 1023) / 1024, 256, 0, stream>>>(eraw, flags, packed);
    sort_kernel<<<(N_EDGES + T_EDGES - 1) / T_EDGES, 256, 0, stream>>>(packed, gbuck, gcur);
    gather_agg<<<NBUCK, 256, 0, stream>>>(x, gbuck, gcur, eps, h);

    const int gemmGrid = (N_NODES / 16 + 3) / 4;  // 782
    gemm_mfma<0><<<gemmGrid, 256, 0, stream>>>(h, W1, b1, nullptr, nullptr, y, sum1, sq1);
    finalize_kernel<<<1, 128, 0, stream>>>(sum1, sq1, g1, be1, scale1, shift1);
    gemm_mfma<1><<<gemmGrid, 256, 0, stream>>>(y, W2, b2, scale1, shift1, y, sum2, sq2);
    finalize_kernel<<<1, 128, 0, stream>>>(sum2, sq2, g2, be2, scale2, shift2);
    output_kernel<<<(N_NODES * DIM / 8 + 255) / 256, 256, 0, stream>>>(y, scale2, shift2, (float*)d_out);
}

// Round 7
// 262.422 us; speedup vs baseline: 3.4227x; 3.4227x over previous
//
#include <hip/hip_runtime.h>
#include <hip/hip_bf16.h>

typedef __hip_bfloat16 bf16;
typedef unsigned short u16;
typedef unsigned int u32;
typedef __attribute__((ext_vector_type(8))) short short8;
typedef __attribute__((ext_vector_type(4))) float floatx4;

#define N_NODES 50000
#define N_EDGES 800000
#define DIM 128
#define NBUCK 391          // ceil(50000/128); bucket = dst >> 7
#define CAP 2560           // per-bucket capacity (mean 2046)
#define T_EDGES 8192       // edges per sort1 block

__device__ __forceinline__ u16 f2bfbits(float f) {
    bf16 h = __float2bfloat16(f);
    return *(u16*)&h;
}
__device__ __forceinline__ unsigned pack2(float a, float b) {
    return (unsigned)f2bfbits(a) | ((unsigned)f2bfbits(b) << 16);
}

// ---------------- detect int64-vs-int32 edge storage + zero cursors/stats ----------------
__global__ void detect_kernel(const int* __restrict__ ei, int* __restrict__ flags,
                              int* __restrict__ gcur, float* __restrict__ stats) {
    int t = threadIdx.x;
    if (t < NBUCK) gcur[t] = 0;
    stats[t] = 0.f;                      // 512 threads == 4*128 stats slots
    if (t == 0) {
        int acc = 0;
        for (int k = 0; k < 64; k++) acc |= ei[2 * k + 1];
        flags[1] = (acc == 0) ? 1 : 0;
    }
}

// ---------------- pack edges: packed[e] = src | (dst << 16) ----------------
__global__ void pack_kernel(const int* __restrict__ ei, const int* __restrict__ flags,
                            u32* __restrict__ packed) {
    int is64 = flags[1];
    int base = blockIdx.x * 1024 + threadIdx.x;
    #pragma unroll
    for (int j = 0; j < 4; j++) {
        int e = base + j * 256;
        if (e < N_EDGES) {
            int js = e, jd = N_EDGES + e;
            if (is64) { js = 2 * e; jd = 2 * (N_EDGES + e); }
            u32 s = (u32)ei[js], d = (u32)ei[jd];
            packed[e] = s | (d << 16);
        }
    }
}

// ---------------- level-1: tile counting-sort into 391 dst-buckets ----------------
__launch_bounds__(256)
__global__ void sort1_kernel(const u32* __restrict__ packed, u32* __restrict__ gbuck,
                             int* __restrict__ gcur) {
    __shared__ int hist[512];
    __shared__ int offs[512];
    __shared__ int partial[256];
    __shared__ int cur[NBUCK];
    __shared__ int gbase[NBUCK];
    __shared__ u32 buf[T_EDGES];
    int t = threadIdx.x;
    int e0 = blockIdx.x * T_EDGES;
    int n = N_EDGES - e0; if (n > T_EDGES) n = T_EDGES;

    for (int i = t; i < 512; i += 256) hist[i] = 0;
    for (int i = t; i < NBUCK; i += 256) cur[i] = 0;
    __syncthreads();

    u32 ed[T_EDGES / 256];
    #pragma unroll
    for (int j = 0; j < T_EDGES / 256; j++) {
        int idx = j * 256 + t;
        if (idx < n) {
            u32 p = packed[e0 + idx];
            ed[j] = p;
            atomicAdd(&hist[p >> 23], 1);   // bucket = dst>>7 = p>>23
        }
    }
    __syncthreads();

    // exclusive scan of hist[512] with 256 threads (2 elems each)
    int a0 = hist[2 * t], a1 = hist[2 * t + 1];
    partial[t] = a0 + a1;
    __syncthreads();
    for (int d = 1; d < 256; d <<= 1) {
        int v = (t >= d) ? partial[t - d] : 0;
        __syncthreads();
        partial[t] += v;
        __syncthreads();
    }
    int ex = partial[t] - (a0 + a1);
    offs[2 * t] = ex; offs[2 * t + 1] = ex + a0;
    __syncthreads();

    // scatter into LDS in bucket order
    #pragma unroll
    for (int j = 0; j < T_EDGES / 256; j++) {
        int idx = j * 256 + t;
        if (idx < n) {
            int b = ed[j] >> 23;
            int s = offs[b] + atomicAdd(&cur[b], 1);
            buf[s] = ed[j];
        }
    }
    // reserve global space per bucket
    for (int i = t; i < NBUCK; i += 256) {
        int c = hist[i];
        gbase[i] = c ? atomicAdd(&gcur[i], c) : 0;
    }
    __syncthreads();

    // copy out contiguous runs (wave per bucket round-robin)
    int wv = t >> 6, lane = t & 63;
    for (int b = wv; b < NBUCK; b += 4) {
        int c = hist[b], o = offs[b];
        long gb = (long)b * CAP + gbase[b];
        for (int j = lane; j < c; j += 64) gbuck[gb + j] = buf[o + j];
    }
}

// ---------------- level-2: in-bucket counting sort by dst&127 -> CSR ----------------
// Block per bucket. All global writes coalesced. nbrs holds src ids at
// bucket-region offsets; starts/counts give per-node segments.
__launch_bounds__(256)
__global__ void sort2_kernel(const u32* __restrict__ gbuck, const int* __restrict__ gcur,
                             u32* __restrict__ nbrs, int* __restrict__ starts,
                             int* __restrict__ counts) {
    __shared__ int cnt[128];
    __shared__ int offs[128];
    __shared__ int cur[128];
    __shared__ u32 buf[CAP];
    __shared__ u32 buf2[CAP];
    int b = blockIdx.x, t = threadIdx.x;
    int n = gcur[b];
    long base = (long)b * CAP;
    if (t < 128) { cnt[t] = 0; cur[t] = 0; }
    __syncthreads();

    for (int i = t; i < n; i += 256) {
        u32 p = gbuck[base + i];
        buf[i] = p;
        atomicAdd(&cnt[(p >> 16) & 127], 1);
    }
    __syncthreads();

    // inclusive scan of cnt -> offs (exclusive)
    if (t < 128) offs[t] = cnt[t];
    __syncthreads();
    for (int d = 1; d < 128; d <<= 1) {
        int v = 0;
        if (t < 128 && t >= d) v = offs[t - d];
        __syncthreads();
        if (t < 128) offs[t] += v;
        __syncthreads();
    }
    // offs[t] now inclusive; convert to exclusive
    if (t < 128) offs[t] -= cnt[t];
    __syncthreads();

    for (int i = t; i < n; i += 256) {
        u32 p = buf[i];
        int d = (p >> 16) & 127;
        int s = offs[d] + atomicAdd(&cur[d], 1);
        buf2[s] = p & 0xFFFF;
    }
    __syncthreads();

    for (int i = t; i < n; i += 256) nbrs[base + i] = buf2[i];
    if (t < 128) {
        starts[b * 128 + t] = (int)(base + offs[t]);
        counts[b * 128 + t] = cnt[t];
    }
}

// ---------------- aggregation: h = (1+eps)*x + sum_{j in N(i)} x_j ----------------
// wave per node; lane = float2 (512 B row). 8x unrolled -> 8 row loads in flight.
__global__ void agg_kernel(const float2* __restrict__ xw, const int* __restrict__ starts,
                           const int* __restrict__ counts, const u32* __restrict__ nbrs,
                           const float* __restrict__ epsp, unsigned* __restrict__ hw) {
    int lane = threadIdx.x & 63;
    int node = blockIdx.x * 4 + (threadIdx.x >> 6);  // 12500 * 4 = 50000 exactly
    float ep1 = 1.0f + epsp[0];
    float2 self = xw[node * 64 + lane];
    float ax = ep1 * self.x, ay = ep1 * self.y;
    int s = starts[node], e = s + counts[node];
    int i = s;
    for (; i + 8 <= e; i += 8) {
        int n0 = nbrs[i],     n1 = nbrs[i + 1], n2 = nbrs[i + 2], n3 = nbrs[i + 3];
        int n4 = nbrs[i + 4], n5 = nbrs[i + 5], n6 = nbrs[i + 6], n7 = nbrs[i + 7];
        float2 u0 = xw[n0 * 64 + lane], u1 = xw[n1 * 64 + lane];
        float2 u2 = xw[n2 * 64 + lane], u3 = xw[n3 * 64 + lane];
        float2 u4 = xw[n4 * 64 + lane], u5 = xw[n5 * 64 + lane];
        float2 u6 = xw[n6 * 64 + lane], u7 = xw[n7 * 64 + lane];
        ax += ((u0.x + u1.x) + (u2.x + u3.x)) + ((u4.x + u5.x) + (u6.x + u7.x));
        ay += ((u0.y + u1.y) + (u2.y + u3.y)) + ((u4.y + u5.y) + (u6.y + u7.y));
    }
    for (; i + 2 <= e; i += 2) {
        int n0 = nbrs[i], n1 = nbrs[i + 1];
        float2 u0 = xw[n0 * 64 + lane], u1 = xw[n1 * 64 + lane];
        ax += u0.x + u1.x; ay += u0.y + u1.y;
    }
    if (i < e) {
        float2 u = xw[nbrs[i] * 64 + lane];
        ax += u.x; ay += u.y;
    }
    hw[node * 64 + lane] = pack2(ax, ay);
}

// ---------------- MFMA GEMM: Y[m][o] = sum_k T(A[m][k]) * W[o][k] + bias[o] ----------------
template<int TRANSFORM>
__launch_bounds__(256)
__global__ void gemm_mfma(const void* Ap, const float* __restrict__ Wp,
                          const float* __restrict__ bias,
                          const float* __restrict__ scale, const float* __restrict__ shift,
                          float* Yp, float* __restrict__ osum, float* __restrict__ osq) {
    __shared__ u16 sW[128 * 136];
    __shared__ float sScale[128], sShift[128], sBias[128], sSum[128], sSq[128];
    int t = threadIdx.x, lane = t & 63, wv = t >> 6;

    #pragma unroll
    for (int it = 0; it < 16; it++) {
        int q = it * 256 + t;
        int r = q >> 5, cq = q & 31;
        floatx4 w = ((const floatx4*)Wp)[q];
        u16 bb[4] = {f2bfbits(w[0]), f2bfbits(w[1]), f2bfbits(w[2]), f2bfbits(w[3])};
        *(uint2*)&sW[r * 136 + cq * 4] = *(uint2*)bb;
    }
    if (t < 128) {
        sSum[t] = 0.f; sSq[t] = 0.f; sBias[t] = bias[t];
        if (TRANSFORM) { sScale[t] = scale[t]; sShift[t] = shift[t]; }
    }
    __syncthreads();

    int tile = blockIdx.x * 4 + wv;
    if (tile < (N_NODES / 16)) {
        int col0 = lane & 15, quad = lane >> 4;
        int mrow = tile * 16 + col0;

        short8 afr[4];
        if (TRANSFORM == 0) {
            const u16* A = (const u16*)Ap;
            #pragma unroll
            for (int ks = 0; ks < 4; ks++)
                afr[ks] = *(const short8*)&A[mrow * DIM + ks * 32 + quad * 8];
        } else {
            const float* A = (const float*)Ap;
            #pragma unroll
            for (int ks = 0; ks < 4; ks++) {
                int kb = ks * 32 + quad * 8;
                floatx4 v0 = *(const floatx4*)&A[mrow * DIM + kb];
                floatx4 v1 = *(const floatx4*)&A[mrow * DIM + kb + 4];
                short8 r;
                #pragma unroll
                for (int j = 0; j < 4; j++) {
                    r[j]     = (short)f2bfbits(fmaxf(fmaf(v0[j], sScale[kb + j],     sShift[kb + j]),     0.f));
                    r[j + 4] = (short)f2bfbits(fmaxf(fmaf(v1[j], sScale[kb + 4 + j], sShift[kb + 4 + j]), 0.f));
                }
                afr[ks] = r;
            }
        }

        floatx4 acc[8];
        #pragma unroll
        for (int nt = 0; nt < 8; nt++) acc[nt] = (floatx4){0.f, 0.f, 0.f, 0.f};
        #pragma unroll
        for (int ks = 0; ks < 4; ks++) {
            #pragma unroll
            for (int nt = 0; nt < 8; nt++) {
                short8 bfr = *(const short8*)&sW[(nt * 16 + col0) * 136 + ks * 32 + quad * 8];
                acc[nt] = __builtin_amdgcn_mfma_f32_16x16x32_bf16(afr[ks], bfr, acc[nt], 0, 0, 0);
            }
        }

        #pragma unroll
        for (int nt = 0; nt < 8; nt++) {
            int col = nt * 16 + col0;
            float bb = sBias[col];
            float o0 = acc[nt][0] + bb, o1 = acc[nt][1] + bb;
            float o2 = acc[nt][2] + bb, o3 = acc[nt][3] + bb;
            int rbase = tile * 16 + quad * 4;
            Yp[(rbase + 0) * DIM + col] = o0;
            Yp[(rbase + 1) * DIM + col] = o1;
            Yp[(rbase + 2) * DIM + col] = o2;
            Yp[(rbase + 3) * DIM + col] = o3;
            float s = o0 + o1 + o2 + o3;
            float q = o0 * o0 + o1 * o1 + o2 * o2 + o3 * o3;
            s += __shfl_xor(s, 16); s += __shfl_xor(s, 32);
            q += __shfl_xor(q, 16); q += __shfl_xor(q, 32);
            if (quad == 0) { atomicAdd(&sSum[col], s); atomicAdd(&sSq[col], q); }
        }
    }
    __syncthreads();
    if (t < 128) { atomicAdd(&osum[t], sSum[t]); atomicAdd(&osq[t], sSq[t]); }
}

__global__ void finalize_kernel(const float* __restrict__ sum, const float* __restrict__ sumsq,
                                const float* __restrict__ gamma, const float* __restrict__ beta,
                                float* __restrict__ scale, float* __restrict__ shift) {
    int c = threadIdx.x;
    if (c < 128) {
        float m = sum[c] * (1.0f / N_NODES);
        float v = sumsq[c] * (1.0f / N_NODES) - m * m;
        v = fmaxf(v, 0.0f);
        float rs = rsqrtf(v + 1e-5f);
        float sc = gamma[c] * rs;
        scale[c] = sc;
        shift[c] = beta[c] - m * sc;
    }
}

__global__ void output_kernel(const float* __restrict__ Y, const float* __restrict__ scale,
                              const float* __restrict__ shift, float* __restrict__ out) {
    int i = (blockIdx.x * blockDim.x + threadIdx.x) * 8;
    if (i >= N_NODES * DIM) return;
    int c = i & 127;
    floatx4 v0 = *(const floatx4*)&Y[i];
    floatx4 v1 = *(const floatx4*)&Y[i + 4];
    floatx4 o0, o1;
    #pragma unroll
    for (int j = 0; j < 4; j++) {
        o0[j] = fmaxf(fmaf(v0[j], scale[c + j],     shift[c + j]),     0.f);
        o1[j] = fmaxf(fmaf(v1[j], scale[c + 4 + j], shift[c + 4 + j]), 0.f);
    }
    *(floatx4*)&out[i] = o0;
    *(floatx4*)&out[i + 4] = o1;
}

extern "C" void kernel_launch(void* const* d_in, const int* in_sizes, int n_in,
                              void* d_out, int out_size, void* d_ws, size_t ws_size,
                              hipStream_t stream) {
    const float* x   = (const float*)d_in[0];
    const int* eraw  = (const int*)d_in[1];
    const float* eps = (const float*)d_in[3];
    const float* W1  = (const float*)d_in[4];
    const float* b1  = (const float*)d_in[5];
    const float* g1  = (const float*)d_in[6];
    const float* be1 = (const float*)d_in[7];
    const float* W2  = (const float*)d_in[8];
    const float* b2  = (const float*)d_in[9];
    const float* g2  = (const float*)d_in[10];
    const float* be2 = (const float*)d_in[11];

    char* ws = (char*)d_ws;
    size_t off = 0;
    unsigned* h = (unsigned*)(ws + off); off += (size_t)N_NODES * DIM * 2;   // bf16, 12.8 MB
    float* y = (float*)(ws + off);       off += (size_t)N_NODES * DIM * 4;   // fp32, 25.6 MB
    float* stats = (float*)(ws + off);   off += 4 * 128 * 4;
    float* sum1 = stats, *sq1 = stats + 128, *sum2 = stats + 256, *sq2 = stats + 384;
    float* scale1 = (float*)(ws + off);  off += 128 * 4;
    float* shift1 = (float*)(ws + off);  off += 128 * 4;
    float* scale2 = (float*)(ws + off);  off += 128 * 4;
    float* shift2 = (float*)(ws + off);  off += 128 * 4;
    u32* packed = (u32*)(ws + off);      off += (size_t)N_EDGES * 4;         // 3.2 MB
    u32* gbuck = (u32*)(ws + off);       off += (size_t)NBUCK * CAP * 4;     // 4.0 MB
    u32* nbrs = (u32*)(ws + off);        off += (size_t)NBUCK * CAP * 4;     // 4.0 MB
    int* starts = (int*)(ws + off);      off += (size_t)NBUCK * 128 * 4;     // 200 KB
    int* counts = (int*)(ws + off);      off += (size_t)NBUCK * 128 * 4;     // 200 KB
    int* gcur = (int*)(ws + off);        off += 512 * 4;
    int* flags = (int*)(ws + off);       off += 16 * 4;

    detect_kernel<<<1, 512, 0, stream>>>(eraw, flags, gcur, stats);
    pack_kernel<<<(N_EDGES + 1023) / 1024, 256, 0, stream>>>(eraw, flags, packed);
    sort1_kernel<<<(N_EDGES + T_EDGES - 1) / T_EDGES, 256, 0, stream>>>(packed, gbuck, gcur);
    sort2_kernel<<<NBUCK, 256, 0, stream>>>(gbuck, gcur, nbrs, starts, counts);
    agg_kernel<<<N_NODES / 4, 256, 0, stream>>>((const float2*)x, starts, counts, nbrs, eps, h);

    const int gemmGrid = (N_NODES / 16 + 3) / 4;  // 782
    gemm_mfma<0><<<gemmGrid, 256, 0, stream>>>(h, W1, b1, nullptr, nullptr, y, sum1, sq1);
    finalize_kernel<<<1, 128, 0, stream>>>(sum1, sq1, g1, be1, scale1, shift1);
    gemm_mfma<1><<<gemmGrid, 256, 0, stream>>>(y, W2, b2, scale1, shift1, y, sum2, sq2);
    finalize_kernel<<<1, 128, 0, stream>>>(sum2, sq2, g2, be2, scale2, shift2);
    output_kernel<<<(N_NODES * DIM / 8 + 255) / 256, 256, 0, stream>>>(y, scale2, shift2, (float*)d_out);
}

// Round 8
// 240.618 us; speedup vs baseline: 3.7328x; 1.0906x over previous
//
#include <hip/hip_runtime.h>
#include <hip/hip_bf16.h>

typedef __hip_bfloat16 bf16;
typedef unsigned short u16;
typedef unsigned int u32;
typedef __attribute__((ext_vector_type(8))) short short8;
typedef __attribute__((ext_vector_type(4))) float floatx4;

#define N_NODES 50000
#define N_EDGES 800000
#define DIM 128
#define NBUCK 391          // ceil(50000/128); bucket = dst >> 7
#define CAP 2560           // per-bucket capacity (mean 2048, sigma ~45)
#define T_EDGES 8192       // edges per sort1 block

__device__ __forceinline__ u16 f2bfbits(float f) {
    bf16 h = __float2bfloat16(f);
    return *(u16*)&h;
}
__device__ __forceinline__ unsigned pack2(float a, float b) {
    return (unsigned)f2bfbits(a) | ((unsigned)f2bfbits(b) << 16);
}
__device__ __forceinline__ float lo2f(u32 u) { u32 v = u << 16; return __builtin_bit_cast(float, v); }
__device__ __forceinline__ float hi2f(u32 u) { u32 v = u & 0xFFFF0000u; return __builtin_bit_cast(float, v); }
__device__ __forceinline__ float b162f(u16 u) { u32 v = (u32)u << 16; return __builtin_bit_cast(float, v); }

// ---------------- detect int64-vs-int32 edge storage + zero cursors/stats ----------------
__global__ void detect_kernel(const int* __restrict__ ei, int* __restrict__ flags,
                              int* __restrict__ gcur, float* __restrict__ stats) {
    int t = threadIdx.x;
    if (t < NBUCK) gcur[t] = 0;
    stats[t] = 0.f;                      // 512 threads == 4*128 stats slots
    if (t == 0) {
        int acc = 0;
        for (int k = 0; k < 64; k++) acc |= ei[2 * k + 1];
        flags[1] = (acc == 0) ? 1 : 0;
    }
}

// ---------------- x fp32 -> bf16 (8 floats / thread) ----------------
__global__ void convert_x(const float* __restrict__ x, u32* __restrict__ xb) {
    int i = (blockIdx.x * 256 + threadIdx.x) * 8;
    floatx4 v0 = *(const floatx4*)&x[i];
    floatx4 v1 = *(const floatx4*)&x[i + 4];
    uint4 r;
    r.x = pack2(v0[0], v0[1]); r.y = pack2(v0[2], v0[3]);
    r.z = pack2(v1[0], v1[1]); r.w = pack2(v1[2], v1[3]);
    *(uint4*)&xb[i / 2] = r;
}

// ---------------- level-1: tile counting-sort into 391 dst-buckets (packs inline) ----------------
__launch_bounds__(256)
__global__ void sort1_kernel(const int* __restrict__ ei, const int* __restrict__ flags,
                             u32* __restrict__ gbuck, int* __restrict__ gcur) {
    __shared__ int hist[512];
    __shared__ int offs[512];
    __shared__ int partial[256];
    __shared__ int cur[NBUCK];
    __shared__ int gbase[NBUCK];
    __shared__ u32 buf[T_EDGES];
    int t = threadIdx.x;
    int is64 = flags[1];
    int e0 = blockIdx.x * T_EDGES;
    int n = N_EDGES - e0; if (n > T_EDGES) n = T_EDGES;

    for (int i = t; i < 512; i += 256) hist[i] = 0;
    for (int i = t; i < NBUCK; i += 256) cur[i] = 0;
    __syncthreads();

    u32 ed[T_EDGES / 256];
    #pragma unroll
    for (int j = 0; j < T_EDGES / 256; j++) {
        int idx = j * 256 + t;
        if (idx < n) {
            int e = e0 + idx;
            int js = e, jd = N_EDGES + e;
            if (is64) { js = 2 * e; jd = 2 * (N_EDGES + e); }
            u32 p = (u32)ei[js] | ((u32)ei[jd] << 16);
            ed[j] = p;
            atomicAdd(&hist[p >> 23], 1);   // bucket = dst>>7 = p>>23
        }
    }
    __syncthreads();

    // exclusive scan of hist[512] with 256 threads (2 elems each)
    int a0 = hist[2 * t], a1 = hist[2 * t + 1];
    partial[t] = a0 + a1;
    __syncthreads();
    for (int d = 1; d < 256; d <<= 1) {
        int v = (t >= d) ? partial[t - d] : 0;
        __syncthreads();
        partial[t] += v;
        __syncthreads();
    }
    int ex = partial[t] - (a0 + a1);
    offs[2 * t] = ex; offs[2 * t + 1] = ex + a0;
    __syncthreads();

    // scatter into LDS in bucket order
    #pragma unroll
    for (int j = 0; j < T_EDGES / 256; j++) {
        int idx = j * 256 + t;
        if (idx < n) {
            int b = ed[j] >> 23;
            int s = offs[b] + atomicAdd(&cur[b], 1);
            buf[s] = ed[j];
        }
    }
    // reserve global space per bucket
    for (int i = t; i < NBUCK; i += 256) {
        int c = hist[i];
        gbase[i] = c ? atomicAdd(&gcur[i], c) : 0;
    }
    __syncthreads();

    // copy out contiguous runs (wave per bucket round-robin)
    int wv = t >> 6, lane = t & 63;
    for (int b = wv; b < NBUCK; b += 4) {
        int c = hist[b], o = offs[b];
        long gb = (long)b * CAP + gbase[b];
        for (int j = lane; j < c; j += 64) gbuck[gb + j] = buf[o + j];
    }
}

// ---------------- level-2: in-bucket counting sort by dst&127 -> CSR ----------------
__launch_bounds__(256)
__global__ void sort2_kernel(const u32* __restrict__ gbuck, const int* __restrict__ gcur,
                             u32* __restrict__ nbrs, int* __restrict__ starts,
                             int* __restrict__ counts) {
    __shared__ int cnt[128];
    __shared__ int offs[128];
    __shared__ int cur[128];
    __shared__ u32 buf[CAP];
    __shared__ u32 buf2[CAP];
    int b = blockIdx.x, t = threadIdx.x;
    int n = gcur[b];
    long base = (long)b * CAP;
    if (t < 128) { cnt[t] = 0; cur[t] = 0; }
    __syncthreads();

    for (int i = t; i < n; i += 256) {
        u32 p = gbuck[base + i];
        buf[i] = p;
        atomicAdd(&cnt[(p >> 16) & 127], 1);
    }
    __syncthreads();

    if (t < 128) offs[t] = cnt[t];
    __syncthreads();
    for (int d = 1; d < 128; d <<= 1) {
        int v = 0;
        if (t < 128 && t >= d) v = offs[t - d];
        __syncthreads();
        if (t < 128) offs[t] += v;
        __syncthreads();
    }
    if (t < 128) offs[t] -= cnt[t];
    __syncthreads();

    for (int i = t; i < n; i += 256) {
        u32 p = buf[i];
        int d = (p >> 16) & 127;
        int s = offs[d] + atomicAdd(&cur[d], 1);
        buf2[s] = p & 0xFFFF;
    }
    __syncthreads();

    for (int i = t; i < n; i += 256) nbrs[base + i] = buf2[i];
    if (t < 128) {
        starts[b * 128 + t] = (int)(base + offs[t]);
        counts[b * 128 + t] = cnt[t];
    }
}

// ---------------- aggregation: h = (1+eps)*x + sum_{j in N(i)} x_j ----------------
// x bf16 (256 B rows). wave per node; lane = 1 u32 = 2 feats. 8 loads in flight.
__global__ void agg_kernel(const u32* __restrict__ xb, const int* __restrict__ starts,
                           const int* __restrict__ counts, const u32* __restrict__ nbrs,
                           const float* __restrict__ epsp, u32* __restrict__ hw) {
    int lane = threadIdx.x & 63;
    int node = blockIdx.x * 4 + (threadIdx.x >> 6);  // 12500 * 4 = 50000 exactly
    float ep1 = 1.0f + epsp[0];
    u32 self = xb[node * 64 + lane];
    float ax = ep1 * lo2f(self), ay = ep1 * hi2f(self);
    int s = starts[node], e = s + counts[node];
    int i = s;
    for (; i + 8 <= e; i += 8) {
        int n0 = nbrs[i],     n1 = nbrs[i + 1], n2 = nbrs[i + 2], n3 = nbrs[i + 3];
        int n4 = nbrs[i + 4], n5 = nbrs[i + 5], n6 = nbrs[i + 6], n7 = nbrs[i + 7];
        u32 u0 = xb[n0 * 64 + lane], u1 = xb[n1 * 64 + lane];
        u32 u2 = xb[n2 * 64 + lane], u3 = xb[n3 * 64 + lane];
        u32 u4 = xb[n4 * 64 + lane], u5 = xb[n5 * 64 + lane];
        u32 u6 = xb[n6 * 64 + lane], u7 = xb[n7 * 64 + lane];
        ax += ((lo2f(u0) + lo2f(u1)) + (lo2f(u2) + lo2f(u3))) +
              ((lo2f(u4) + lo2f(u5)) + (lo2f(u6) + lo2f(u7)));
        ay += ((hi2f(u0) + hi2f(u1)) + (hi2f(u2) + hi2f(u3))) +
              ((hi2f(u4) + hi2f(u5)) + (hi2f(u6) + hi2f(u7)));
    }
    for (; i + 2 <= e; i += 2) {
        u32 u0 = xb[nbrs[i] * 64 + lane], u1 = xb[nbrs[i + 1] * 64 + lane];
        ax += lo2f(u0) + lo2f(u1); ay += hi2f(u0) + hi2f(u1);
    }
    if (i < e) {
        u32 u = xb[nbrs[i] * 64 + lane];
        ax += lo2f(u); ay += hi2f(u);
    }
    hw[node * 64 + lane] = pack2(ax, ay);
}

// ---------------- MFMA GEMM: Y[m][o] = sum_k T(A[m][k]) * W[o][k] + bias[o] ----------------
// A bf16; TRANSFORM=1 applies relu(a*scale[k]+shift[k]) to A (fused BN1+ReLU).
// Output Y bf16 (u16 scalar stores); BN stats accumulated from fp32 pre-rounding values.
template<int TRANSFORM>
__launch_bounds__(256)
__global__ void gemm_mfma(const u16* __restrict__ Ap, const float* __restrict__ Wp,
                          const float* __restrict__ bias,
                          const float* __restrict__ scale, const float* __restrict__ shift,
                          u16* __restrict__ Yp, float* __restrict__ osum, float* __restrict__ osq) {
    __shared__ u16 sW[128 * 136];
    __shared__ float sScale[128], sShift[128], sBias[128], sSum[128], sSq[128];
    int t = threadIdx.x, lane = t & 63, wv = t >> 6;

    #pragma unroll
    for (int it = 0; it < 16; it++) {
        int q = it * 256 + t;
        int r = q >> 5, cq = q & 31;
        floatx4 w = ((const floatx4*)Wp)[q];
        u16 bb[4] = {f2bfbits(w[0]), f2bfbits(w[1]), f2bfbits(w[2]), f2bfbits(w[3])};
        *(uint2*)&sW[r * 136 + cq * 4] = *(uint2*)bb;
    }
    if (t < 128) {
        sSum[t] = 0.f; sSq[t] = 0.f; sBias[t] = bias[t];
        if (TRANSFORM) { sScale[t] = scale[t]; sShift[t] = shift[t]; }
    }
    __syncthreads();

    int tile = blockIdx.x * 4 + wv;
    if (tile < (N_NODES / 16)) {
        int col0 = lane & 15, quad = lane >> 4;
        int mrow = tile * 16 + col0;

        short8 afr[4];
        #pragma unroll
        for (int ks = 0; ks < 4; ks++) {
            int kb = ks * 32 + quad * 8;
            short8 a = *(const short8*)&Ap[mrow * DIM + kb];
            if (TRANSFORM) {
                short8 r;
                #pragma unroll
                for (int j = 0; j < 8; j++) {
                    float f = b162f((u16)a[j]);
                    r[j] = (short)f2bfbits(fmaxf(fmaf(f, sScale[kb + j], sShift[kb + j]), 0.f));
                }
                afr[ks] = r;
            } else {
                afr[ks] = a;
            }
        }

        floatx4 acc[8];
        #pragma unroll
        for (int nt = 0; nt < 8; nt++) acc[nt] = (floatx4){0.f, 0.f, 0.f, 0.f};
        #pragma unroll
        for (int ks = 0; ks < 4; ks++) {
            #pragma unroll
            for (int nt = 0; nt < 8; nt++) {
                short8 bfr = *(const short8*)&sW[(nt * 16 + col0) * 136 + ks * 32 + quad * 8];
                acc[nt] = __builtin_amdgcn_mfma_f32_16x16x32_bf16(afr[ks], bfr, acc[nt], 0, 0, 0);
            }
        }

        #pragma unroll
        for (int nt = 0; nt < 8; nt++) {
            int col = nt * 16 + col0;
            float bb = sBias[col];
            float o0 = acc[nt][0] + bb, o1 = acc[nt][1] + bb;
            float o2 = acc[nt][2] + bb, o3 = acc[nt][3] + bb;
            int rbase = tile * 16 + quad * 4;
            Yp[(rbase + 0) * DIM + col] = f2bfbits(o0);
            Yp[(rbase + 1) * DIM + col] = f2bfbits(o1);
            Yp[(rbase + 2) * DIM + col] = f2bfbits(o2);
            Yp[(rbase + 3) * DIM + col] = f2bfbits(o3);
            float s = o0 + o1 + o2 + o3;
            float q = o0 * o0 + o1 * o1 + o2 * o2 + o3 * o3;
            s += __shfl_xor(s, 16); s += __shfl_xor(s, 32);
            q += __shfl_xor(q, 16); q += __shfl_xor(q, 32);
            if (quad == 0) { atomicAdd(&sSum[col], s); atomicAdd(&sSq[col], q); }
        }
    }
    __syncthreads();
    if (t < 128) { atomicAdd(&osum[t], sSum[t]); atomicAdd(&osq[t], sSq[t]); }
}

__global__ void finalize_kernel(const float* __restrict__ sum, const float* __restrict__ sumsq,
                                const float* __restrict__ gamma, const float* __restrict__ beta,
                                float* __restrict__ scale, float* __restrict__ shift) {
    int c = threadIdx.x;
    if (c < 128) {
        float m = sum[c] * (1.0f / N_NODES);
        float v = sumsq[c] * (1.0f / N_NODES) - m * m;
        v = fmaxf(v, 0.0f);
        float rs = rsqrtf(v + 1e-5f);
        float sc = gamma[c] * rs;
        scale[c] = sc;
        shift[c] = beta[c] - m * sc;
    }
}

// ---------------- final BN2 + ReLU: y2 bf16 -> out fp32 (8 elems/thread) ----------------
__global__ void output_kernel(const u32* __restrict__ Y, const float* __restrict__ scale,
                              const float* __restrict__ shift, float* __restrict__ out) {
    int i = (blockIdx.x * 256 + threadIdx.x) * 8;
    if (i >= N_NODES * DIM) return;
    int c = i & 127;
    uint4 v = *(const uint4*)&Y[i / 2];
    u32 w[4] = {v.x, v.y, v.z, v.w};
    floatx4 o0, o1;
    #pragma unroll
    for (int j = 0; j < 4; j++) {
        float lo = lo2f(w[j]), hi = hi2f(w[j]);
        float r0 = fmaxf(fmaf(lo, scale[c + 2 * j],     shift[c + 2 * j]),     0.f);
        float r1 = fmaxf(fmaf(hi, scale[c + 2 * j + 1], shift[c + 2 * j + 1]), 0.f);
        if (j < 2) { o0[2 * j] = r0; o0[2 * j + 1] = r1; }
        else       { o1[2 * (j - 2)] = r0; o1[2 * (j - 2) + 1] = r1; }
    }
    *(floatx4*)&out[i] = o0;
    *(floatx4*)&out[i + 4] = o1;
}

extern "C" void kernel_launch(void* const* d_in, const int* in_sizes, int n_in,
                              void* d_out, int out_size, void* d_ws, size_t ws_size,
                              hipStream_t stream) {
    const float* x   = (const float*)d_in[0];
    const int* eraw  = (const int*)d_in[1];
    const float* eps = (const float*)d_in[3];
    const float* W1  = (const float*)d_in[4];
    const float* b1  = (const float*)d_in[5];
    const float* g1  = (const float*)d_in[6];
    const float* be1 = (const float*)d_in[7];
    const float* W2  = (const float*)d_in[8];
    const float* b2  = (const float*)d_in[9];
    const float* g2  = (const float*)d_in[10];
    const float* be2 = (const float*)d_in[11];

    char* ws = (char*)d_ws;
    size_t off = 0;
    u32* xb = (u32*)(ws + off);          off += (size_t)N_NODES * DIM * 2;   // bf16 x, 12.8 MB
    u32* h1 = (u32*)(ws + off);          off += (size_t)N_NODES * DIM * 2;   // bf16 h, 12.8 MB
    u16* y1 = (u16*)(ws + off);          off += (size_t)N_NODES * DIM * 2;   // bf16 y1
    u16* y2 = (u16*)(ws + off);          off += (size_t)N_NODES * DIM * 2;   // bf16 y2
    float* stats = (float*)(ws + off);   off += 4 * 128 * 4;
    float* sum1 = stats, *sq1 = stats + 128, *sum2 = stats + 256, *sq2 = stats + 384;
    float* scale1 = (float*)(ws + off);  off += 128 * 4;
    float* shift1 = (float*)(ws + off);  off += 128 * 4;
    float* scale2 = (float*)(ws + off);  off += 128 * 4;
    float* shift2 = (float*)(ws + off);  off += 128 * 4;
    u32* gbuck = (u32*)(ws + off);       off += (size_t)NBUCK * CAP * 4;     // 4.0 MB
    u32* nbrs = (u32*)(ws + off);        off += (size_t)NBUCK * CAP * 4;     // 4.0 MB
    int* starts = (int*)(ws + off);      off += (size_t)NBUCK * 128 * 4;
    int* counts = (int*)(ws + off);      off += (size_t)NBUCK * 128 * 4;
    int* gcur = (int*)(ws + off);        off += 512 * 4;
    int* flags = (int*)(ws + off);       off += 16 * 4;

    detect_kernel<<<1, 512, 0, stream>>>(eraw, flags, gcur, stats);
    convert_x<<<N_NODES * DIM / (8 * 256), 256, 0, stream>>>(x, xb);
    sort1_kernel<<<(N_EDGES + T_EDGES - 1) / T_EDGES, 256, 0, stream>>>(eraw, flags, gbuck, gcur);
    sort2_kernel<<<NBUCK, 256, 0, stream>>>(gbuck, gcur, nbrs, starts, counts);
    agg_kernel<<<N_NODES / 4, 256, 0, stream>>>(xb, starts, counts, nbrs, eps, h1);

    const int gemmGrid = (N_NODES / 16 + 3) / 4;  // 782
    gemm_mfma<0><<<gemmGrid, 256, 0, stream>>>((const u16*)h1, W1, b1, nullptr, nullptr, y1, sum1, sq1);
    finalize_kernel<<<1, 128, 0, stream>>>(sum1, sq1, g1, be1, scale1, shift1);
    gemm_mfma<1><<<gemmGrid, 256, 0, stream>>>(y1, W2, b2, scale1, shift1, y2, sum2, sq2);
    finalize_kernel<<<1, 128, 0, stream>>>(sum2, sq2, g2, be2, scale2, shift2);
    output_kernel<<<N_NODES * DIM / (8 * 256), 256, 0, stream>>>((const u32*)y2, scale2, shift2, (float*)d_out);
}

// Round 9
// 234.245 us; speedup vs baseline: 3.8344x; 1.0272x over previous
//
#include <hip/hip_runtime.h>
#include <hip/hip_bf16.h>

typedef __hip_bfloat16 bf16;
typedef unsigned short u16;
typedef unsigned int u32;
typedef __attribute__((ext_vector_type(8))) short short8;
typedef __attribute__((ext_vector_type(4))) float floatx4;

#define N_NODES 50000
#define N_EDGES 800000
#define DIM 128
#define NBUCK 391          // ceil(50000/128); bucket = dst >> 7
#define CAP 2560           // per-bucket capacity (mean 2048, sigma ~45)
#define T_EDGES 8192       // edges per sort1 block

__device__ __forceinline__ u16 f2bfbits(float f) {
    bf16 h = __float2bfloat16(f);
    return *(u16*)&h;
}
__device__ __forceinline__ unsigned pack2(float a, float b) {
    return (unsigned)f2bfbits(a) | ((unsigned)f2bfbits(b) << 16);
}
__device__ __forceinline__ float lo2f(u32 u) { u32 v = u << 16; return __builtin_bit_cast(float, v); }
__device__ __forceinline__ float hi2f(u32 u) { u32 v = u & 0xFFFF0000u; return __builtin_bit_cast(float, v); }
__device__ __forceinline__ float b162f(u16 u) { u32 v = (u32)u << 16; return __builtin_bit_cast(float, v); }

// ---------------- prep: x fp32->bf16, zero cursors/stats, detect ei storage ----------------
__global__ void prep_kernel(const float* __restrict__ x, u32* __restrict__ xb,
                            const int* __restrict__ ei, int* __restrict__ flags,
                            int* __restrict__ gcur, float* __restrict__ stats) {
    int t = threadIdx.x;
    if (blockIdx.x == 0) {
        if (t < NBUCK) gcur[t] = 0;
        if (t + 256 < NBUCK) gcur[t + 256] = 0;
        stats[t] = 0.f; stats[t + 256] = 0.f;
        if (t == 0) {
            int acc = 0;
            for (int k = 0; k < 64; k++) acc |= ei[2 * k + 1];
            flags[1] = (acc == 0) ? 1 : 0;
        }
    }
    int i = (blockIdx.x * 256 + t) * 8;
    floatx4 v0 = *(const floatx4*)&x[i];
    floatx4 v1 = *(const floatx4*)&x[i + 4];
    uint4 r;
    r.x = pack2(v0[0], v0[1]); r.y = pack2(v0[2], v0[3]);
    r.z = pack2(v1[0], v1[1]); r.w = pack2(v1[2], v1[3]);
    *(uint4*)&xb[i / 2] = r;
}

// ---------------- level-1: tile counting-sort into 391 dst-buckets (packs inline) ----------------
__launch_bounds__(256)
__global__ void sort1_kernel(const int* __restrict__ ei, const int* __restrict__ flags,
                             u32* __restrict__ gbuck, int* __restrict__ gcur) {
    __shared__ int hist[512];
    __shared__ int offs[512];
    __shared__ int partial[256];
    __shared__ int cur[NBUCK];
    __shared__ int gbase[NBUCK];
    __shared__ u32 buf[T_EDGES];
    int t = threadIdx.x;
    int is64 = flags[1];
    int e0 = blockIdx.x * T_EDGES;
    int n = N_EDGES - e0; if (n > T_EDGES) n = T_EDGES;

    for (int i = t; i < 512; i += 256) hist[i] = 0;
    for (int i = t; i < NBUCK; i += 256) cur[i] = 0;
    __syncthreads();

    u32 ed[T_EDGES / 256];
    #pragma unroll
    for (int j = 0; j < T_EDGES / 256; j++) {
        int idx = j * 256 + t;
        if (idx < n) {
            int e = e0 + idx;
            int js = e, jd = N_EDGES + e;
            if (is64) { js = 2 * e; jd = 2 * (N_EDGES + e); }
            u32 p = (u32)ei[js] | ((u32)ei[jd] << 16);
            ed[j] = p;
            atomicAdd(&hist[p >> 23], 1);   // bucket = dst>>7 = p>>23
        }
    }
    __syncthreads();

    // exclusive scan of hist[512] with 256 threads (2 elems each)
    int a0 = hist[2 * t], a1 = hist[2 * t + 1];
    partial[t] = a0 + a1;
    __syncthreads();
    for (int d = 1; d < 256; d <<= 1) {
        int v = (t >= d) ? partial[t - d] : 0;
        __syncthreads();
        partial[t] += v;
        __syncthreads();
    }
    int ex = partial[t] - (a0 + a1);
    offs[2 * t] = ex; offs[2 * t + 1] = ex + a0;
    __syncthreads();

    // scatter into LDS in bucket order
    #pragma unroll
    for (int j = 0; j < T_EDGES / 256; j++) {
        int idx = j * 256 + t;
        if (idx < n) {
            int b = ed[j] >> 23;
            int s = offs[b] + atomicAdd(&cur[b], 1);
            buf[s] = ed[j];
        }
    }
    // reserve global space per bucket
    for (int i = t; i < NBUCK; i += 256) {
        int c = hist[i];
        gbase[i] = c ? atomicAdd(&gcur[i], c) : 0;
    }
    __syncthreads();

    // copy out contiguous runs (wave per bucket round-robin)
    int wv = t >> 6, lane = t & 63;
    for (int b = wv; b < NBUCK; b += 4) {
        int c = hist[b], o = offs[b];
        long gb = (long)b * CAP + gbase[b];
        for (int j = lane; j < c; j += 64) gbuck[gb + j] = buf[o + j];
    }
}

// ---------------- level-2: in-bucket counting sort by dst&127 -> CSR ----------------
__launch_bounds__(256)
__global__ void sort2_kernel(const u32* __restrict__ gbuck, const int* __restrict__ gcur,
                             u32* __restrict__ nbrs, int* __restrict__ starts,
                             int* __restrict__ counts) {
    __shared__ int cnt[128];
    __shared__ int offs[128];
    __shared__ int cur[128];
    __shared__ u32 buf[CAP];
    __shared__ u32 buf2[CAP];
    int b = blockIdx.x, t = threadIdx.x;
    int n = gcur[b];
    long base = (long)b * CAP;
    if (t < 128) { cnt[t] = 0; cur[t] = 0; }
    __syncthreads();

    for (int i = t; i < n; i += 256) {
        u32 p = gbuck[base + i];
        buf[i] = p;
        atomicAdd(&cnt[(p >> 16) & 127], 1);
    }
    __syncthreads();

    if (t < 128) offs[t] = cnt[t];
    __syncthreads();
    for (int d = 1; d < 128; d <<= 1) {
        int v = 0;
        if (t < 128 && t >= d) v = offs[t - d];
        __syncthreads();
        if (t < 128) offs[t] += v;
        __syncthreads();
    }
    if (t < 128) offs[t] -= cnt[t];
    __syncthreads();

    for (int i = t; i < n; i += 256) {
        u32 p = buf[i];
        int d = (p >> 16) & 127;
        int s = offs[d] + atomicAdd(&cur[d], 1);
        buf2[s] = p & 0xFFFF;
    }
    __syncthreads();

    for (int i = t; i < n; i += 256) nbrs[base + i] = buf2[i];
    if (t < 128) {
        starts[b * 128 + t] = (int)(base + offs[t]);
        counts[b * 128 + t] = cnt[t];
    }
}

// ---------------- aggregation: h = (1+eps)*x + sum_{j in N(i)} x_j ----------------
// x bf16 (256 B rows). wave per node; lane = 1 u32 = 2 feats.
// 16x unrolled main loop -> 16 independent row loads in flight (mean degree = 16).
__global__ void agg_kernel(const u32* __restrict__ xb, const int* __restrict__ starts,
                           const int* __restrict__ counts, const u32* __restrict__ nbrs,
                           const float* __restrict__ epsp, u32* __restrict__ hw) {
    int lane = threadIdx.x & 63;
    int node = blockIdx.x * 4 + (threadIdx.x >> 6);  // 12500 * 4 = 50000 exactly
    float ep1 = 1.0f + epsp[0];
    u32 self = xb[node * 64 + lane];
    float ax = ep1 * lo2f(self), ay = ep1 * hi2f(self);
    int s = starts[node], e = s + counts[node];
    int i = s;
    for (; i + 16 <= e; i += 16) {
        int nn[16];
        u32 u[16];
        #pragma unroll
        for (int j = 0; j < 16; j++) nn[j] = nbrs[i + j];
        #pragma unroll
        for (int j = 0; j < 16; j++) u[j] = xb[nn[j] * 64 + lane];
        #pragma unroll
        for (int j = 0; j < 16; j++) { ax += lo2f(u[j]); ay += hi2f(u[j]); }
    }
    for (; i + 8 <= e; i += 8) {
        int nn[8];
        u32 u[8];
        #pragma unroll
        for (int j = 0; j < 8; j++) nn[j] = nbrs[i + j];
        #pragma unroll
        for (int j = 0; j < 8; j++) u[j] = xb[nn[j] * 64 + lane];
        #pragma unroll
        for (int j = 0; j < 8; j++) { ax += lo2f(u[j]); ay += hi2f(u[j]); }
    }
    for (; i + 2 <= e; i += 2) {
        u32 u0 = xb[nbrs[i] * 64 + lane], u1 = xb[nbrs[i + 1] * 64 + lane];
        ax += lo2f(u0) + lo2f(u1); ay += hi2f(u0) + hi2f(u1);
    }
    if (i < e) {
        u32 u = xb[nbrs[i] * 64 + lane];
        ax += lo2f(u); ay += hi2f(u);
    }
    hw[node * 64 + lane] = pack2(ax, ay);
}

// ---------------- MFMA GEMM: Y[m][o] = sum_k T(A[m][k]) * W[o][k] + bias[o] ----------------
// A bf16; TRANSFORM=1 computes BN1 scale/shift inline from global sums (fused finalize)
// and applies relu(a*scale[k]+shift[k]) to A. Output Y bf16; stats from fp32 values.
template<int TRANSFORM>
__launch_bounds__(256)
__global__ void gemm_mfma(const u16* __restrict__ Ap, const float* __restrict__ Wp,
                          const float* __restrict__ bias,
                          const float* __restrict__ gamma, const float* __restrict__ beta,
                          const float* __restrict__ gsum, const float* __restrict__ gsq,
                          u16* __restrict__ Yp, float* __restrict__ osum, float* __restrict__ osq) {
    __shared__ u16 sW[128 * 136];
    __shared__ float sScale[128], sShift[128], sBias[128], sSum[128], sSq[128];
    int t = threadIdx.x, lane = t & 63, wv = t >> 6;

    #pragma unroll
    for (int it = 0; it < 16; it++) {
        int q = it * 256 + t;
        int r = q >> 5, cq = q & 31;
        floatx4 w = ((const floatx4*)Wp)[q];
        u16 bb[4] = {f2bfbits(w[0]), f2bfbits(w[1]), f2bfbits(w[2]), f2bfbits(w[3])};
        *(uint2*)&sW[r * 136 + cq * 4] = *(uint2*)bb;
    }
    if (t < 128) {
        sSum[t] = 0.f; sSq[t] = 0.f; sBias[t] = bias[t];
        if (TRANSFORM) {
            float m = gsum[t] * (1.0f / N_NODES);
            float v = fmaxf(gsq[t] * (1.0f / N_NODES) - m * m, 0.0f);
            float rs = rsqrtf(v + 1e-5f);
            float sc = gamma[t] * rs;
            sScale[t] = sc;
            sShift[t] = beta[t] - m * sc;
        }
    }
    __syncthreads();

    int tile = blockIdx.x * 4 + wv;
    if (tile < (N_NODES / 16)) {
        int col0 = lane & 15, quad = lane >> 4;
        int mrow = tile * 16 + col0;

        short8 afr[4];
        #pragma unroll
        for (int ks = 0; ks < 4; ks++) {
            int kb = ks * 32 + quad * 8;
            short8 a = *(const short8*)&Ap[mrow * DIM + kb];
            if (TRANSFORM) {
                short8 r;
                #pragma unroll
                for (int j = 0; j < 8; j++) {
                    float f = b162f((u16)a[j]);
                    r[j] = (short)f2bfbits(fmaxf(fmaf(f, sScale[kb + j], sShift[kb + j]), 0.f));
                }
                afr[ks] = r;
            } else {
                afr[ks] = a;
            }
        }

        floatx4 acc[8];
        #pragma unroll
        for (int nt = 0; nt < 8; nt++) acc[nt] = (floatx4){0.f, 0.f, 0.f, 0.f};
        #pragma unroll
        for (int ks = 0; ks < 4; ks++) {
            #pragma unroll
            for (int nt = 0; nt < 8; nt++) {
                short8 bfr = *(const short8*)&sW[(nt * 16 + col0) * 136 + ks * 32 + quad * 8];
                acc[nt] = __builtin_amdgcn_mfma_f32_16x16x32_bf16(afr[ks], bfr, acc[nt], 0, 0, 0);
            }
        }

        #pragma unroll
        for (int nt = 0; nt < 8; nt++) {
            int col = nt * 16 + col0;
            float bb = sBias[col];
            float o0 = acc[nt][0] + bb, o1 = acc[nt][1] + bb;
            float o2 = acc[nt][2] + bb, o3 = acc[nt][3] + bb;
            int rbase = tile * 16 + quad * 4;
            Yp[(rbase + 0) * DIM + col] = f2bfbits(o0);
            Yp[(rbase + 1) * DIM + col] = f2bfbits(o1);
            Yp[(rbase + 2) * DIM + col] = f2bfbits(o2);
            Yp[(rbase + 3) * DIM + col] = f2bfbits(o3);
            float s = o0 + o1 + o2 + o3;
            float q = o0 * o0 + o1 * o1 + o2 * o2 + o3 * o3;
            s += __shfl_xor(s, 16); s += __shfl_xor(s, 32);
            q += __shfl_xor(q, 16); q += __shfl_xor(q, 32);
            if (quad == 0) { atomicAdd(&sSum[col], s); atomicAdd(&sSq[col], q); }
        }
    }
    __syncthreads();
    if (t < 128) { atomicAdd(&osum[t], sSum[t]); atomicAdd(&osq[t], sSq[t]); }
}

// ---------------- final BN2 + ReLU (inline finalize2): y2 bf16 -> out fp32 ----------------
__global__ void output_kernel(const u32* __restrict__ Y,
                              const float* __restrict__ gsum, const float* __restrict__ gsq,
                              const float* __restrict__ gamma, const float* __restrict__ beta,
                              float* __restrict__ out) {
    __shared__ float sScale[128], sShift[128];
    int t = threadIdx.x;
    if (t < 128) {
        float m = gsum[t] * (1.0f / N_NODES);
        float v = fmaxf(gsq[t] * (1.0f / N_NODES) - m * m, 0.0f);
        float rs = rsqrtf(v + 1e-5f);
        float sc = gamma[t] * rs;
        sScale[t] = sc;
        sShift[t] = beta[t] - m * sc;
    }
    __syncthreads();
    int i = (blockIdx.x * 256 + t) * 8;
    int c = i & 127;
    uint4 v = *(const uint4*)&Y[i / 2];
    u32 w[4] = {v.x, v.y, v.z, v.w};
    floatx4 o0, o1;
    #pragma unroll
    for (int j = 0; j < 4; j++) {
        float lo = lo2f(w[j]), hi = hi2f(w[j]);
        float r0 = fmaxf(fmaf(lo, sScale[c + 2 * j],     sShift[c + 2 * j]),     0.f);
        float r1 = fmaxf(fmaf(hi, sScale[c + 2 * j + 1], sShift[c + 2 * j + 1]), 0.f);
        if (j < 2) { o0[2 * j] = r0; o0[2 * j + 1] = r1; }
        else       { o1[2 * (j - 2)] = r0; o1[2 * (j - 2) + 1] = r1; }
    }
    *(floatx4*)&out[i] = o0;
    *(floatx4*)&out[i + 4] = o1;
}

extern "C" void kernel_launch(void* const* d_in, const int* in_sizes, int n_in,
                              void* d_out, int out_size, void* d_ws, size_t ws_size,
                              hipStream_t stream) {
    const float* x   = (const float*)d_in[0];
    const int* eraw  = (const int*)d_in[1];
    const float* eps = (const float*)d_in[3];
    const float* W1  = (const float*)d_in[4];
    const float* b1  = (const float*)d_in[5];
    const float* g1  = (const float*)d_in[6];
    const float* be1 = (const float*)d_in[7];
    const float* W2  = (const float*)d_in[8];
    const float* b2  = (const float*)d_in[9];
    const float* g2  = (const float*)d_in[10];
    const float* be2 = (const float*)d_in[11];

    char* ws = (char*)d_ws;
    size_t off = 0;
    u32* xb = (u32*)(ws + off);          off += (size_t)N_NODES * DIM * 2;   // bf16 x, 12.8 MB
    u32* h1 = (u32*)(ws + off);          off += (size_t)N_NODES * DIM * 2;   // bf16 h, 12.8 MB
    u16* y1 = (u16*)(ws + off);          off += (size_t)N_NODES * DIM * 2;   // bf16 y1
    u16* y2 = (u16*)(ws + off);          off += (size_t)N_NODES * DIM * 2;   // bf16 y2
    float* stats = (float*)(ws + off);   off += 4 * 128 * 4;
    float* sum1 = stats, *sq1 = stats + 128, *sum2 = stats + 256, *sq2 = stats + 384;
    u32* gbuck = (u32*)(ws + off);       off += (size_t)NBUCK * CAP * 4;     // 4.0 MB
    u32* nbrs = (u32*)(ws + off);        off += (size_t)NBUCK * CAP * 4;     // 4.0 MB
    int* starts = (int*)(ws + off);      off += (size_t)NBUCK * 128 * 4;
    int* counts = (int*)(ws + off);      off += (size_t)NBUCK * 128 * 4;
    int* gcur = (int*)(ws + off);        off += 512 * 4;
    int* flags = (int*)(ws + off);       off += 16 * 4;

    prep_kernel<<<N_NODES * DIM / (8 * 256), 256, 0, stream>>>(x, xb, eraw, flags, gcur, stats);
    sort1_kernel<<<(N_EDGES + T_EDGES - 1) / T_EDGES, 256, 0, stream>>>(eraw, flags, gbuck, gcur);
    sort2_kernel<<<NBUCK, 256, 0, stream>>>(gbuck, gcur, nbrs, starts, counts);
    agg_kernel<<<N_NODES / 4, 256, 0, stream>>>(xb, starts, counts, nbrs, eps, h1);

    const int gemmGrid = (N_NODES / 16 + 3) / 4;  // 782
    gemm_mfma<0><<<gemmGrid, 256, 0, stream>>>((const u16*)h1, W1, b1,
                                               nullptr, nullptr, nullptr, nullptr, y1, sum1, sq1);
    gemm_mfma<1><<<gemmGrid, 256, 0, stream>>>(y1, W2, b2,
                                               g1, be1, sum1, sq1, y2, sum2, sq2);
    output_kernel<<<N_NODES * DIM / (8 * 256), 256, 0, stream>>>((const u32*)y2, sum2, sq2,
                                                                 g2, be2, (float*)d_out);
}